// Round 1
// baseline (246.431 us; speedup 1.0000x reference)
//
#include <hip/hip_runtime.h>
#include <math.h>

#define SEQ 65536
#define FEAT 512
#define NCH 256
#define CHUNK 256
#define THRES1 0.8f
#define THRES_UP 0.5f
#define NEGINF -1e30f

// ---------------- K1: a = sigmoid(h @ W + b), one wave per row ----------------
__global__ __launch_bounds__(256) void k_matvec(const float* __restrict__ h,
                                                const float* __restrict__ W,
                                                const float* __restrict__ b,
                                                float* __restrict__ a) {
    int wave = threadIdx.x >> 6;
    int lane = threadIdx.x & 63;
    int row  = blockIdx.x * 4 + wave;
    const float4* hp = (const float4*)(h + (size_t)row * FEAT);
    const float4* wp = (const float4*)W;
    int base = lane * 2;  // each lane: elements [lane*8, lane*8+8)
    float4 h0 = hp[base], h1 = hp[base + 1];
    float4 w0 = wp[base], w1 = wp[base + 1];
    float s = h0.x * w0.x + h0.y * w0.y + h0.z * w0.z + h0.w * w0.w
            + h1.x * w1.x + h1.y * w1.y + h1.z * w1.z + h1.w * w1.w;
    #pragma unroll
    for (int off = 32; off; off >>= 1) s += __shfl_down(s, off, 64);
    if (lane == 0) a[row] = 1.0f / (1.0f + expf(-(s + b[0])));
}

// ------- K2: per-chunk local scans: segmented run-max, last-trigger idx, last-fall idx -------
__global__ __launch_bounds__(256) void k_local(const float* __restrict__ u_pred,
                                               const float* __restrict__ label,
                                               float* __restrict__ m_loc, int* __restrict__ openA,
                                               int* __restrict__ ltLoc, int* __restrict__ lfExcl,
                                               float* __restrict__ lastm, int* __restrict__ lastopen,
                                               int* __restrict__ lastgate, int* __restrict__ trigLast,
                                               int* __restrict__ fallLast) {
    __shared__ float su[256];
    __shared__ float sm[256];
    __shared__ int   sr[256];
    __shared__ int   st[256];
    __shared__ int   sf[256];
    int t = threadIdx.x, c = blockIdx.x;
    int i = c * CHUNK + t;
    float u = u_pred[i];
    su[t] = u;
    __syncthreads();
    bool gate = u >= THRES_UP;
    bool gprevLocal = (t > 0) && (su[t - 1] >= THRES_UP);
    bool gprev = (t > 0) ? gprevLocal : ((i > 0) && (u_pred[i - 1] >= THRES_UP));
    bool fall = gprev && !gate;
    bool trig = label[i] >= THRES1;

    // segmented max init: flag=1 blocks absorbing left (segment boundary)
    sm[t] = gate ? u : NEGINF;
    sr[t] = gate ? ((t > 0 && !gprevLocal) ? 1 : 0) : 1;
    st[t] = trig ? i : -1;
    sf[t] = fall ? i : -1;
    __syncthreads();
    for (int d = 1; d < 256; d <<= 1) {
        float lm = NEGINF; int lr = 0, lt = -1, lf = -1;
        bool act = t >= d;
        if (act) { lm = sm[t - d]; lr = sr[t - d]; lt = st[t - d]; lf = sf[t - d]; }
        __syncthreads();
        if (act) {
            if (!sr[t]) sm[t] = fmaxf(lm, sm[t]);
            sr[t] |= lr;
            st[t] = max(st[t], lt);
            sf[t] = max(sf[t], lf);
        }
        __syncthreads();
    }
    m_loc[i]  = sm[t];
    openA[i]  = (sr[t] == 0 && gate) ? 1 : 0;
    ltLoc[i]  = st[t];
    lfExcl[i] = (t == 0) ? -1 : sf[t - 1];
    if (t == 255) {
        lastm[c]    = sm[255];
        lastopen[c] = (sr[255] == 0 && gate) ? 1 : 0;
        lastgate[c] = gate ? 1 : 0;
        trigLast[c] = st[255];
        fallLast[c] = sf[255];
    }
}

// ------- K3: cross-chunk: incoming run-max (max-plus affine scan), trigIn/fallIn (max scans) -------
__global__ __launch_bounds__(256) void k_mid1(const float* __restrict__ lastm,
                                              const int* __restrict__ lastopen,
                                              const int* __restrict__ lastgate,
                                              const int* __restrict__ trigLast,
                                              const int* __restrict__ fallLast,
                                              float* __restrict__ inc, int* __restrict__ trigIn,
                                              int* __restrict__ fallIn,
                                              float* __restrict__ losscnt) {
    __shared__ float sA[256], sB[256];
    __shared__ int   st[256], sf[256];
    int t = threadIdx.x;
    bool lg = lastgate[t] != 0;
    sA[t] = lg ? lastm[t] : NEGINF;
    sB[t] = (lg && lastopen[t]) ? 0.0f : NEGINF;
    st[t] = trigLast[t];
    sf[t] = fallLast[t];
    __syncthreads();
    for (int d = 1; d < 256; d <<= 1) {
        float lA = NEGINF, lB = NEGINF; int lt = -1, lf = -1;
        bool act = t >= d;
        if (act) { lA = sA[t - d]; lB = sB[t - d]; lt = st[t - d]; lf = sf[t - d]; }
        __syncthreads();
        if (act) {
            float nA = fmaxf(sA[t], sB[t] + lA);   // compose right∘left (max-plus)
            float nB = fmaxf(sB[t] + lB, NEGINF);
            sA[t] = nA; sB[t] = nB;
            st[t] = max(st[t], lt);
            sf[t] = max(sf[t], lf);
        }
        __syncthreads();
    }
    inc[t]    = (t == 0) ? NEGINF : fmaxf(sA[t - 1], sB[t - 1] + NEGINF);
    trigIn[t] = (t == 0) ? -1 : st[t - 1];
    fallIn[t] = (t == 0) ? -1 : sf[t - 1];
    if (t == 0) { losscnt[0] = 0.0f; losscnt[1] = 0.0f; }
}

// ------- K4: finalize up_hat; per-chunk affine scan of alpha pairs -------
__global__ __launch_bounds__(256) void k_uphat_alpha(const float* __restrict__ u_pred,
                                                     const float* __restrict__ a,
                                                     const float* __restrict__ m_loc,
                                                     const int* __restrict__ openA,
                                                     const float* __restrict__ inc,
                                                     float* __restrict__ Pc, float* __restrict__ Qc,
                                                     float* __restrict__ Pch, float* __restrict__ Qch,
                                                     float* __restrict__ out) {
    __shared__ float sc[256], sd[256];
    int t = threadIdx.x, c = blockIdx.x;
    int i = c * CHUNK + t;
    float u = u_pred[i];
    bool gate = u >= THRES_UP;
    float uh = gate ? (openA[i] ? fmaxf(m_loc[i], inc[c]) : m_loc[i]) : u;
    out[3 * SEQ + i] = uh;   // up_hats
    out[2 * SEQ + i] = u;    // u_pred passthrough
    sc[t] = uh;
    sd[t] = (1.0f - uh) * a[i];
    __syncthreads();
    for (int d = 1; d < 256; d <<= 1) {
        float lc = 1.0f, ld = 0.0f;
        bool act = t >= d;
        if (act) { lc = sc[t - d]; ld = sd[t - d]; }
        __syncthreads();
        if (act) { sd[t] = sc[t] * ld + sd[t]; sc[t] = sc[t] * lc; }
        __syncthreads();
    }
    Pc[i] = sc[t];
    Qc[i] = sd[t];
    if (t == 255) { Pch[c] = sc[255]; Qch[c] = sd[255]; }
}

// ------- tiny affine scan over 256 chunk summaries (used for alphaIn and yIn) -------
__global__ __launch_bounds__(256) void k_mid_affine(const float* __restrict__ P,
                                                    const float* __restrict__ Q,
                                                    float* __restrict__ res) {
    __shared__ float sc[256], sd[256];
    int t = threadIdx.x;
    sc[t] = P[t]; sd[t] = Q[t];
    __syncthreads();
    for (int d = 1; d < 256; d <<= 1) {
        float lc = 1.0f, ld = 0.0f;
        bool act = t >= d;
        if (act) { lc = sc[t - d]; ld = sd[t - d]; }
        __syncthreads();
        if (act) { sd[t] = sc[t] * ld + sd[t]; sc[t] = sc[t] * lc; }
        __syncthreads();
    }
    res[t] = (t == 0) ? 0.0f : sd[t - 1];
}

// ------- K6: finalize alpha; per-chunk affine scan of y pairs (writes into Pc/Qc, Pch/Qch) -------
__global__ __launch_bounds__(256) void k_alpha_y(float* __restrict__ Pc, float* __restrict__ Qc,
                                                 const float* __restrict__ alphaIn,
                                                 float* __restrict__ out,
                                                 float* __restrict__ Ech, float* __restrict__ Fch) {
    __shared__ float sc[256], sd[256];
    int t = threadIdx.x, c = blockIdx.x;
    int i = c * CHUNK + t;
    float al = Pc[i] * alphaIn[c] + Qc[i];
    out[SEQ + i] = al;  // alphas
    float uh = out[3 * SEQ + i];
    bool gate = uh >= THRES_UP;
    sc[t] = gate ? (1.0f - al) : 0.0f;
    sd[t] = gate ? al * uh : 0.0f;
    __syncthreads();
    for (int d = 1; d < 256; d <<= 1) {
        float lc = 1.0f, ld = 0.0f;
        bool act = t >= d;
        if (act) { lc = sc[t - d]; ld = sd[t - d]; }
        __syncthreads();
        if (act) { sd[t] = sc[t] * ld + sd[t]; sc[t] = sc[t] * lc; }
        __syncthreads();
    }
    Pc[i] = sc[t];  // Ec
    Qc[i] = sd[t];  // Fc
    if (t == 255) { Ech[c] = sc[255]; Fch[c] = sd[255]; }
}

// ------- K8: finalize y -------
__global__ __launch_bounds__(256) void k_yfinal(const float* __restrict__ Ec,
                                                const float* __restrict__ Fc,
                                                const float* __restrict__ yIn,
                                                float* __restrict__ out) {
    int t = threadIdx.x, c = blockIdx.x;
    int i = c * CHUNK + t;
    out[i] = Ec[i] * yIn[c] + Fc[i];  // ys
}

// ------- K9: loss/cnt at gate falling edges -------
__global__ __launch_bounds__(256) void k_loss(const float* __restrict__ u_pred,
                                              const float* __restrict__ label,
                                              const float* __restrict__ thres2,
                                              const int* __restrict__ ltLoc,
                                              const int* __restrict__ lfExcl,
                                              const int* __restrict__ trigIn,
                                              const int* __restrict__ fallIn,
                                              const float* __restrict__ y,
                                              float* __restrict__ out) {
    int t = threadIdx.x, c = blockIdx.x;
    int i = c * CHUNK + t;
    float u = u_pred[i];
    bool gate = u >= THRES_UP;
    bool gprev = (i > 0) && (u_pred[i - 1] >= THRES_UP);
    bool fall = gprev && !gate;
    float contrib = 0.0f;
    int flag = 0;
    if (fall) {
        int j  = max(ltLoc[i], trigIn[c]);    // last label-trigger <= i
        int pf = max(lfExcl[i], fallIn[c]);   // last fall < i
        float lc = 0.0f;
        if (j > pf) {
            bool gj = u_pred[j] >= THRES_UP;
            float d = y[j] - label[j];
            lc = gj ? d * d : -1.0f;
        }
        bool isneg = (lc == -1.0f);
        bool nonzero = (lc != 0.0f);
        if (!isneg) {
            if (nonzero) { contrib = lc; flag = 1; }           // * R, R = 1.0
            else {
                float ypre = y[i - 1];
                if (ypre >= THRES1) {
                    float t2 = thres2[(i < 59) ? i : 59];
                    float d2 = ypre - t2;
                    contrib = d2 * d2; flag = 1;
                }
            }
        }
    }
    #pragma unroll
    for (int off = 32; off; off >>= 1) {
        contrib += __shfl_down(contrib, off, 64);
        flag    += __shfl_down(flag, off, 64);
    }
    if ((t & 63) == 0) {
        atomicAdd(&out[4 * SEQ], contrib);
        atomicAdd(&out[4 * SEQ + 1], (float)flag);
    }
}

extern "C" void kernel_launch(void* const* d_in, const int* in_sizes, int n_in,
                              void* d_out, int out_size, void* d_ws, size_t ws_size,
                              hipStream_t stream) {
    const float* h      = (const float*)d_in[0];
    const float* W      = (const float*)d_in[1];
    const float* b      = (const float*)d_in[2];
    const float* u_pred = (const float*)d_in[4];
    const float* label  = (const float*)d_in[5];
    const float* thres2 = (const float*)d_in[6];
    float* out  = (float*)d_out;
    float* base = (float*)d_ws;

    float* a      = base;
    float* m_loc  = base + SEQ;
    float* Pc     = base + 2 * SEQ;
    float* Qc     = base + 3 * SEQ;
    int*   openA  = (int*)(base + 4 * (size_t)SEQ);
    int*   ltLoc  = (int*)(base + 5 * (size_t)SEQ);
    int*   lfExcl = (int*)(base + 6 * (size_t)SEQ);
    float* sums   = base + 7 * (size_t)SEQ;
    float* lastm   = sums;
    float* Pch     = sums + NCH;
    float* Qch     = sums + 2 * NCH;
    float* inc     = sums + 3 * NCH;
    float* alphaIn = sums + 4 * NCH;
    float* yIn     = sums + 5 * NCH;
    int*   lastopen = (int*)(sums + 6 * NCH);
    int*   lastgate = (int*)(sums + 7 * NCH);
    int*   trigLast = (int*)(sums + 8 * NCH);
    int*   fallLast = (int*)(sums + 9 * NCH);
    int*   trigIn   = (int*)(sums + 10 * NCH);
    int*   fallIn   = (int*)(sums + 11 * NCH);

    k_matvec<<<SEQ / 4, 256, 0, stream>>>(h, W, b, a);
    k_local<<<NCH, CHUNK, 0, stream>>>(u_pred, label, m_loc, openA, ltLoc, lfExcl,
                                       lastm, lastopen, lastgate, trigLast, fallLast);
    k_mid1<<<1, NCH, 0, stream>>>(lastm, lastopen, lastgate, trigLast, fallLast,
                                  inc, trigIn, fallIn, out + 4 * SEQ);
    k_uphat_alpha<<<NCH, CHUNK, 0, stream>>>(u_pred, a, m_loc, openA, inc, Pc, Qc, Pch, Qch, out);
    k_mid_affine<<<1, NCH, 0, stream>>>(Pch, Qch, alphaIn);
    k_alpha_y<<<NCH, CHUNK, 0, stream>>>(Pc, Qc, alphaIn, out, Pch, Qch);
    k_mid_affine<<<1, NCH, 0, stream>>>(Pch, Qch, yIn);
    k_yfinal<<<NCH, CHUNK, 0, stream>>>(Pc, Qc, yIn, out);
    k_loss<<<NCH, CHUNK, 0, stream>>>(u_pred, label, thres2, ltLoc, lfExcl, trigIn, fallIn, out, out);
}